// Round 1
// baseline (185.259 us; speedup 1.0000x reference)
//
#include <hip/hip_runtime.h>
#include <hip/hip_bf16.h>

// SupCon loss, N=8192, D=128, T=0.1.
// Pipeline: memset ws accumulators -> normalize(fp32->bf16) -> main (MFMA Gram +
// streaming exp/pos accumulation, column-split atomics) -> finalize (loss + sum).
//
// Math: loss_i = (cnt_i*lse_i - sum_pos s_ij)/(cnt_i+tiny), lse_i = 10 + log(sum_{j!=i} exp(s_ij-10)).
// Row-max subtraction in the reference cancels exactly; constant shift 10 (=max possible s) is stable.

typedef __bf16 bf16_t;
typedef __bf16 bf16x2 __attribute__((ext_vector_type(2)));
typedef __bf16 bf16x8 __attribute__((ext_vector_type(8)));
typedef float f32x4 __attribute__((ext_vector_type(4)));

#define DIM 128
#define CSPLIT 8          // column splits per 64-row block -> 1024 blocks total
#define SMALL_VAL 1.17549435e-38f

// --- normalize: one wave per row, float2 per lane, write bf16 ---
__global__ __launch_bounds__(256) void normalize_kernel(const float* __restrict__ emb,
                                                        bf16_t* __restrict__ xbf) {
    int row  = blockIdx.x * 4 + (threadIdx.x >> 6);
    int lane = threadIdx.x & 63;
    const float2* src = (const float2*)(emb + (size_t)row * DIM);
    float2 v = src[lane];
    float ss = v.x * v.x + v.y * v.y;
#pragma unroll
    for (int m = 1; m < 64; m <<= 1) ss += __shfl_xor(ss, m, 64);
    float inv = 1.0f / fmaxf(sqrtf(ss), 1e-12f);
    bf16x2 o;
    o.x = (bf16_t)(v.x * inv);
    o.y = (bf16_t)(v.y * inv);
    ((bf16x2*)(xbf + (size_t)row * DIM))[lane] = o;
}

// --- main: each wave owns 16 rows, sweeps a 1/CSPLIT column chunk in 16-col MFMA tiles ---
// MFMA 16x16x32 bf16. A-frag: lane holds X[rowbase + (lane&15)][k = (lane>>4)*8 + j].
// B-frag (Gram: B = X^T) loads with the IDENTICAL pattern from the column rows.
// C layout: col = lane&15, row = (lane>>4)*4 + reg.
__global__ __launch_bounds__(256) void supcon_main(const bf16_t* __restrict__ xbf,
                                                   const int* __restrict__ labels,
                                                   float* __restrict__ se_acc,
                                                   float* __restrict__ ps_acc,
                                                   float* __restrict__ pc_acc,
                                                   int N) {
    int cb   = blockIdx.x & (CSPLIT - 1);
    int rb   = blockIdx.x >> 3;            // CSPLIT == 8
    int wv   = threadIdx.x >> 6;
    int lane = threadIdx.x & 63;
    int cl   = lane & 15;
    int quad = lane >> 4;
    int rowbase = rb * 64 + wv * 16;

    const bf16x8* Arow = (const bf16x8*)(xbf + (size_t)(rowbase + cl) * DIM);
    bf16x8 a0 = Arow[0 + quad];
    bf16x8 a1 = Arow[4 + quad];
    bf16x8 a2 = Arow[8 + quad];
    bf16x8 a3 = Arow[12 + quad];

    int labr[4];
#pragma unroll
    for (int r = 0; r < 4; ++r) labr[r] = labels[rowbase + quad * 4 + r];

    float se[4] = {0.f, 0.f, 0.f, 0.f};
    float ps[4] = {0.f, 0.f, 0.f, 0.f};
    float pc[4] = {0.f, 0.f, 0.f, 0.f};

    int chunk = N / CSPLIT;
    int j0 = cb * chunk;
    for (int jb = j0; jb < j0 + chunk; jb += 16) {
        const bf16x8* Brow = (const bf16x8*)(xbf + (size_t)(jb + cl) * DIM);
        bf16x8 b0 = Brow[0 + quad];
        bf16x8 b1 = Brow[4 + quad];
        bf16x8 b2 = Brow[8 + quad];
        bf16x8 b3 = Brow[12 + quad];
        int labc = labels[jb + cl];

        f32x4 acc = {0.f, 0.f, 0.f, 0.f};
        acc = __builtin_amdgcn_mfma_f32_16x16x32_bf16(a0, b0, acc, 0, 0, 0);
        acc = __builtin_amdgcn_mfma_f32_16x16x32_bf16(a1, b1, acc, 0, 0, 0);
        acc = __builtin_amdgcn_mfma_f32_16x16x32_bf16(a2, b2, acc, 0, 0, 0);
        acc = __builtin_amdgcn_mfma_f32_16x16x32_bf16(a3, b3, acc, 0, 0, 0);

        if (jb == rowbase) {   // wave-uniform: the one tile containing this wave's diagonal
#pragma unroll
            for (int r = 0; r < 4; ++r) {
                float cv = acc[r];
                bool isdiag = (jb + cl) == (rowbase + quad * 4 + r);
                float e = isdiag ? 0.f : __expf(fmaf(cv, 10.f, -10.f));
                bool same = (labc == labr[r]) && !isdiag;
                se[r] += e;
                if (same) { ps[r] += cv; pc[r] += 1.f; }
            }
        } else {
#pragma unroll
            for (int r = 0; r < 4; ++r) {
                float cv = acc[r];
                float e = __expf(fmaf(cv, 10.f, -10.f));
                bool same = (labc == labr[r]);
                se[r] += e;
                if (same) { ps[r] += cv; pc[r] += 1.f; }
            }
        }
    }

    // reduce across the 16 lanes sharing the same 4 rows (xor over low 4 lane bits)
#pragma unroll
    for (int r = 0; r < 4; ++r) {
#pragma unroll
        for (int m = 1; m < 16; m <<= 1) {
            se[r] += __shfl_xor(se[r], m, 64);
            ps[r] += __shfl_xor(ps[r], m, 64);
            pc[r] += __shfl_xor(pc[r], m, 64);
        }
    }
    if (cl == 0) {
#pragma unroll
        for (int r = 0; r < 4; ++r) {
            int row = rowbase + quad * 4 + r;
            atomicAdd(&se_acc[row], se[r]);
            atomicAdd(&ps_acc[row], ps[r]);
            atomicAdd(&pc_acc[row], pc[r]);
        }
    }
}

// --- finalize: per-row loss, wave-reduce, atomic into scalar out ---
__global__ __launch_bounds__(256) void finalize_kernel(const float* __restrict__ se_acc,
                                                       const float* __restrict__ ps_acc,
                                                       const float* __restrict__ pc_acc,
                                                       float* __restrict__ out, int N) {
    int i = blockIdx.x * 256 + threadIdx.x;
    float loss = 0.f;
    if (i < N) {
        float c   = pc_acc[i];
        float lse = __logf(se_acc[i]) + 10.f;          // back to unshifted log-sum-exp
        float p   = ps_acc[i] * 10.f;                  // accumulated cos -> logits
        loss = (c * lse - p) / (c + SMALL_VAL);
    }
#pragma unroll
    for (int m = 1; m < 64; m <<= 1) loss += __shfl_xor(loss, m, 64);
    if ((threadIdx.x & 63) == 0) atomicAdd(out, loss);
}

extern "C" void kernel_launch(void* const* d_in, const int* in_sizes, int n_in,
                              void* d_out, int out_size, void* d_ws, size_t ws_size,
                              hipStream_t stream) {
    const float* emb   = (const float*)d_in[0];
    const int* labels  = (const int*)d_in[1];
    int N = in_sizes[1];                 // 8192

    char* ws = (char*)d_ws;
    bf16_t* xbf = (bf16_t*)ws;
    size_t xbytes = (size_t)N * DIM * sizeof(bf16_t);    // 2 MB
    float* se = (float*)(ws + xbytes);
    float* psum = se + N;
    float* pcnt = psum + N;

    hipMemsetAsync(se, 0, 3 * (size_t)N * sizeof(float), stream);
    hipMemsetAsync(d_out, 0, sizeof(float), stream);

    normalize_kernel<<<N / 4, 256, 0, stream>>>(emb, xbf);
    supcon_main<<<(N / 64) * CSPLIT, 256, 0, stream>>>(xbf, labels, se, psum, pcnt, N);
    finalize_kernel<<<(N + 255) / 256, 256, 0, stream>>>(se, psum, pcnt, (float*)d_out, N);
}

// Round 2
// 144.330 us; speedup vs baseline: 1.2836x; 1.2836x over previous
//
#include <hip/hip_runtime.h>
#include <hip/hip_bf16.h>

// SupCon loss, N=8192, D=128, T=0.1.
// R1: 32x32x16 MFMA (32 rows/wave, 2x arithmetic intensity), register
// double-buffered B frags, pos-count via label histogram (removed from hot loop).
//
// Math: loss_i = (cnt_i*lse_i - sum_pos s_ij)/(cnt_i+tiny),
//       lse_i = 10 + log(sum_{j!=i} exp(s_ij-10)); constant shift is exact
//       (row-max subtraction cancels; s <= 10 always).

typedef __bf16 bf16_t;
typedef __bf16 bf16x2 __attribute__((ext_vector_type(2)));
typedef __bf16 bf16x8 __attribute__((ext_vector_type(8)));
typedef float f32x16 __attribute__((ext_vector_type(16)));

#define DIM 128
#define CSPLIT 16         // column splits; 64 row-blocks * 16 = 1024 blocks
#define SMALL_VAL 1.17549435e-38f
#define LOG2E_10 14.4269504089f   // 10 * log2(e): exp(10cv-10) = exp2(cv*LOG2E_10 - LOG2E_10)

// --- normalize + label histogram: one wave per row ---
__global__ __launch_bounds__(256) void normalize_kernel(const float* __restrict__ emb,
                                                        bf16_t* __restrict__ xbf,
                                                        const int* __restrict__ labels,
                                                        int* __restrict__ hist) {
    int row  = blockIdx.x * 4 + (threadIdx.x >> 6);
    int lane = threadIdx.x & 63;
    const float2* src = (const float2*)(emb + (size_t)row * DIM);
    float2 v = src[lane];
    float ss = v.x * v.x + v.y * v.y;
#pragma unroll
    for (int m = 1; m < 64; m <<= 1) ss += __shfl_xor(ss, m, 64);
    float inv = 1.0f / fmaxf(sqrtf(ss), 1e-12f);
    bf16x2 o;
    o.x = (bf16_t)(v.x * inv);
    o.y = (bf16_t)(v.y * inv);
    ((bf16x2*)(xbf + (size_t)row * DIM))[lane] = o;
    if (lane == 0) atomicAdd(&hist[labels[row]], 1);
}

__device__ inline void loadB(bf16x8* dst, const bf16_t* __restrict__ xbf, int row, int h) {
    const bf16x8* p = (const bf16x8*)(xbf + (size_t)row * DIM) + h;
#pragma unroll
    for (int f = 0; f < 8; ++f) dst[f] = p[2 * f];
}

// --- main: wave owns 32 rows (one 32x32 MFMA C tile), block owns 128 rows.
// A/B frags loaded with IDENTICAL per-lane pattern (Gram symmetry: any shared
// k-permutation cancels in the dot product).
// C layout (m74/m101): col = lane&31, row = (reg&3) + 8*(reg>>2) + 4*(lane>>5).
__global__ __launch_bounds__(256) void supcon_main(const bf16_t* __restrict__ xbf,
                                                   const int* __restrict__ labels,
                                                   float* __restrict__ se_acc,
                                                   float* __restrict__ ps_acc,
                                                   int N) {
    int cb   = blockIdx.x & (CSPLIT - 1);
    int rb   = blockIdx.x >> 4;
    int wv   = threadIdx.x >> 6;
    int lane = threadIdx.x & 63;
    int c    = lane & 31;
    int h    = lane >> 5;
    int rowbase = rb * 128 + wv * 32;

    bf16x8 a[8];
    loadB(a, xbf, rowbase + c, h);

    int labr[16];
#pragma unroll
    for (int r = 0; r < 16; ++r)
        labr[r] = labels[rowbase + (r & 3) + 8 * (r >> 2) + 4 * h];

    float se[16], ps[16];
#pragma unroll
    for (int r = 0; r < 16; ++r) { se[r] = 0.f; ps[r] = 0.f; }

    int chunk = N / CSPLIT;            // 512
    int j0 = cb * chunk;
    int jend = j0 + chunk;

    bf16x8 b[8];
    loadB(b, xbf, j0 + c, h);
    int labc = labels[j0 + c];

    for (int jb = j0; jb < jend; jb += 32) {
        f32x16 acc;
#pragma unroll
        for (int r = 0; r < 16; ++r) acc[r] = 0.f;
#pragma unroll
        for (int f = 0; f < 8; ++f)
            acc = __builtin_amdgcn_mfma_f32_32x32x16_bf16(a[f], b[f], acc, 0, 0, 0);

        int labc_cur = labc;
        // prefetch next iteration's B while epilogue runs (wrap on last iter)
        int jn = (jb + 32 < jend) ? jb + 32 : j0;
        bf16x8 bn[8];
        loadB(bn, xbf, jn + c, h);
        labc = labels[jn + c];

        if (jb == rowbase) {   // wave-uniform: tile containing this wave's diagonal
#pragma unroll
            for (int r = 0; r < 16; ++r) {
                float cv = acc[r];
                bool isdiag = c == ((r & 3) + 8 * (r >> 2) + 4 * h);
                float e = isdiag ? 0.f : exp2f(fmaf(cv, LOG2E_10, -LOG2E_10));
                bool same = (labc_cur == labr[r]) && !isdiag;
                se[r] += e;
                ps[r] += same ? cv : 0.f;
            }
        } else {
#pragma unroll
            for (int r = 0; r < 16; ++r) {
                float cv = acc[r];
                float e = exp2f(fmaf(cv, LOG2E_10, -LOG2E_10));
                bool same = (labc_cur == labr[r]);
                se[r] += e;
                ps[r] += same ? cv : 0.f;
            }
        }
#pragma unroll
        for (int f = 0; f < 8; ++f) b[f] = bn[f];
    }

    // reduce across the 32 lanes sharing each row (xor masks stay within half)
#pragma unroll
    for (int r = 0; r < 16; ++r) {
#pragma unroll
        for (int m = 1; m < 32; m <<= 1) {
            se[r] += __shfl_xor(se[r], m, 64);
            ps[r] += __shfl_xor(ps[r], m, 64);
        }
    }
    if (c == 0) {
#pragma unroll
        for (int r = 0; r < 16; ++r) {
            int row = rowbase + (r & 3) + 8 * (r >> 2) + 4 * h;
            atomicAdd(&se_acc[row], se[r]);
            atomicAdd(&ps_acc[row], ps[r]);
        }
    }
}

// --- finalize: per-row loss from (se, ps, hist), wave-reduce, atomic sum ---
__global__ __launch_bounds__(256) void finalize_kernel(const float* __restrict__ se_acc,
                                                       const float* __restrict__ ps_acc,
                                                       const int* __restrict__ hist,
                                                       const int* __restrict__ labels,
                                                       float* __restrict__ out, int N) {
    int i = blockIdx.x * 256 + threadIdx.x;
    float loss = 0.f;
    if (i < N) {
        float cnt = (float)(hist[labels[i]] - 1);
        float lse = __logf(se_acc[i]) + 10.f;
        float p   = ps_acc[i] * 10.f;
        loss = (cnt * lse - p) / (cnt + SMALL_VAL);
    }
#pragma unroll
    for (int m = 1; m < 64; m <<= 1) loss += __shfl_xor(loss, m, 64);
    if ((threadIdx.x & 63) == 0) atomicAdd(out, loss);
}

extern "C" void kernel_launch(void* const* d_in, const int* in_sizes, int n_in,
                              void* d_out, int out_size, void* d_ws, size_t ws_size,
                              hipStream_t stream) {
    const float* emb  = (const float*)d_in[0];
    const int* labels = (const int*)d_in[1];
    int N = in_sizes[1];               // 8192

    char* ws = (char*)d_ws;
    bf16_t* xbf = (bf16_t*)ws;
    size_t xbytes = (size_t)N * DIM * sizeof(bf16_t);     // 2 MB
    float* se   = (float*)(ws + xbytes);
    float* psum = se + N;
    int*   hist = (int*)(psum + N);                        // 1024 bins

    hipMemsetAsync(se, 0, (2 * (size_t)N + 1024) * sizeof(float), stream);
    hipMemsetAsync(d_out, 0, sizeof(float), stream);

    normalize_kernel<<<N / 4, 256, 0, stream>>>(emb, xbf, labels, hist);
    supcon_main<<<(N / 128) * CSPLIT, 256, 0, stream>>>(xbf, labels, se, psum, N);
    finalize_kernel<<<(N + 255) / 256, 256, 0, stream>>>(se, psum, hist, labels, (float*)d_out, N);
}

// Round 3
// 117.098 us; speedup vs baseline: 1.5821x; 1.2326x over previous
//
#include <hip/hip_runtime.h>
#include <hip/hip_bf16.h>

// SupCon loss, N=8192, D=128, T=0.1.
// R2: swizzled X layout (MFMA fragment order -> fully coalesced 1KB wave loads),
// ps via class-sum trick (hot loop = se only, 3 ops/elem, branch-free; diagonal
// subtracted in finalize), pipelined epilogue + B ping-pong, 4 graph nodes.
//
// Math: loss_i = (cnt_i*lse_i - ps_i)/(cnt_i+tiny)
//   lse_i = 10 + ln(sum_{j!=i} e^{s_ij-10})   (constant shift exact; s<=10)
//   ps_i  = 10*(x_i . csum[lab_i] - x_i . x_i)
//   sum_j e^{s_ij-10} accumulated INCLUDING diagonal; diag e^{10*selfdot-10}
//   subtracted in finalize (same bf16 inputs -> error ~1e-5, threshold 1536).

typedef __bf16 bf16_t;
typedef __bf16 bf16x2 __attribute__((ext_vector_type(2)));
typedef __bf16 bf16x8 __attribute__((ext_vector_type(8)));
typedef float f32x16 __attribute__((ext_vector_type(16)));

#define NN 8192
#define DIM 128
#define NCLASS 1024              // labels in [0,1000)
#define CSPLIT 32                // column splits -> grid 64*32 = 2048 blocks
#define ITERS ((NN / CSPLIT) / 32)   // 8 iterations per wave, full unroll
#define SMALL_VAL 1.17549435e-38f
#define L2E10 14.4269504089f     // 10*log2(e): e^(10c-10) = 2^(c*L2E10 - L2E10)
#define LN2 0.69314718056f

// Swizzled layout (elements): X[row][d] at (row>>5)*4096 + (d>>4)*512 + ((d>>3)&1)*256 + (row&31)*8 + (d&7)
// => MFMA frag f for 32-row block blk: 1KB contiguous at blk*4096 + f*512, lane offset h*256+c*8.

// --- normalize + swizzle store + class-sum + histogram + out zeroing ---
__global__ __launch_bounds__(256) void normalize_kernel(const float* __restrict__ emb,
                                                        const int* __restrict__ labels,
                                                        bf16_t* __restrict__ xsw,
                                                        float* __restrict__ csum,
                                                        int* __restrict__ hist,
                                                        float* __restrict__ out) {
    int row  = blockIdx.x * 4 + (threadIdx.x >> 6);
    int lane = threadIdx.x & 63;
    float2 v = ((const float2*)emb)[row * 64 + lane];      // dims 2*lane, 2*lane+1
    float ss = v.x * v.x + v.y * v.y;
#pragma unroll
    for (int m = 1; m < 64; m <<= 1) ss += __shfl_xor(ss, m, 64);
    float inv = 1.0f / fmaxf(sqrtf(ss), 1e-12f);
    bf16_t bx = (bf16_t)(v.x * inv), by = (bf16_t)(v.y * inv);
    int f = lane >> 3, hh = (lane >> 2) & 1, j = (lane & 3) << 1;
    bf16x2 o; o.x = bx; o.y = by;
    *(bf16x2*)(xsw + ((size_t)(row >> 5) * 4096) + f * 512 + hh * 256 + (row & 31) * 8 + j) = o;
    int lab = labels[row];
    atomicAdd(&csum[lab * DIM + 2 * lane],     (float)bx);
    atomicAdd(&csum[lab * DIM + 2 * lane + 1], (float)by);
    if (lane == 0) atomicAdd(&hist[lab], 1);
    if (blockIdx.x == 0 && threadIdx.x == 0) *out = 0.f;
}

// --- main: wave = one 32x32 C tile row-band, sweeps 8 column tiles.
// A/B frags use identical lane patterns (Gram symmetry: shared k-permutation cancels).
// C layout (m74/m101): col = lane&31, row = (r&3) + 8*(r>>2) + 4*(lane>>5).
__global__ __launch_bounds__(256, 3) void supcon_main(const bf16_t* __restrict__ xsw,
                                                      float* __restrict__ se_acc) {
    int cb   = blockIdx.x & (CSPLIT - 1);
    int rb   = blockIdx.x >> 5;
    int wv   = threadIdx.x >> 6;
    int lane = threadIdx.x & 63;
    int c    = lane & 31;
    int h    = lane >> 5;
    int laneoff = h * 256 + c * 8;
    int rowblk  = rb * 4 + wv;

    const bf16_t* abase = xsw + (size_t)rowblk * 4096 + laneoff;
    bf16x8 a[8];
#pragma unroll
    for (int f = 0; f < 8; ++f) a[f] = *(const bf16x8*)(abase + f * 512);

    const bf16_t* bbase = xsw + (size_t)(cb * ITERS) * 4096 + laneoff;

    float se[16];
#pragma unroll
    for (int r = 0; r < 16; ++r) se[r] = 0.f;

    bf16x8 b0[8], b1[8];
#pragma unroll
    for (int f = 0; f < 8; ++f) b0[f] = *(const bf16x8*)(bbase + f * 512);

    f32x16 accA;
#pragma unroll
    for (int r = 0; r < 16; ++r) accA[r] = 0.f;
#pragma unroll
    for (int f = 0; f < 8; ++f)
        accA = __builtin_amdgcn_mfma_f32_32x32x16_bf16(a[f], b0[f], accA, 0, 0, 0);

#pragma unroll
    for (int f = 0; f < 8; ++f) b1[f] = *(const bf16x8*)(bbase + 4096 + f * 512);

#pragma unroll
    for (int t = 1; t < ITERS; ++t) {
        f32x16 accB;
#pragma unroll
        for (int r = 0; r < 16; ++r) accB[r] = 0.f;
        if (t & 1) {
#pragma unroll
            for (int f = 0; f < 8; ++f)
                accB = __builtin_amdgcn_mfma_f32_32x32x16_bf16(a[f], b1[f], accB, 0, 0, 0);
        } else {
#pragma unroll
            for (int f = 0; f < 8; ++f)
                accB = __builtin_amdgcn_mfma_f32_32x32x16_bf16(a[f], b0[f], accB, 0, 0, 0);
        }
        if (t + 1 < ITERS) {                    // compile-time resolved (full unroll)
            const bf16_t* nb = bbase + (size_t)(t + 1) * 4096;
            if (t & 1) {
#pragma unroll
                for (int f = 0; f < 8; ++f) b0[f] = *(const bf16x8*)(nb + f * 512);
            } else {
#pragma unroll
                for (int f = 0; f < 8; ++f) b1[f] = *(const bf16x8*)(nb + f * 512);
            }
        }
        // epilogue of previous tile — independent of accB's MFMA chain, interleaves
#pragma unroll
        for (int r = 0; r < 16; ++r)
            se[r] += exp2f(fmaf(accA[r], L2E10, -L2E10));
        accA = accB;
    }
#pragma unroll
    for (int r = 0; r < 16; ++r)
        se[r] += exp2f(fmaf(accA[r], L2E10, -L2E10));

    // reduce across the 32 columns (xor masks stay within each 32-lane half)
#pragma unroll
    for (int r = 0; r < 16; ++r) {
        float vv = se[r];
#pragma unroll
        for (int m = 1; m < 32; m <<= 1) vv += __shfl_xor(vv, m, 64);
        se[r] = vv;
    }
    if (c == 0) {
        int rowbase = rowblk * 32 + 4 * h;
#pragma unroll
        for (int r = 0; r < 16; ++r)
            atomicAdd(&se_acc[rowbase + (r & 3) + 8 * (r >> 2)], se[r]);
    }
}

// --- finalize: per-row loss; one wave per 8 rows; 256 block atomics total ---
__global__ __launch_bounds__(256) void finalize_kernel(const bf16_t* __restrict__ xsw,
                                                       const float* __restrict__ se_acc,
                                                       const float* __restrict__ csum,
                                                       const int* __restrict__ hist,
                                                       const int* __restrict__ labels,
                                                       float* __restrict__ out) {
    __shared__ float part[4];
    int wv = threadIdx.x >> 6, lane = threadIdx.x & 63;
    int wid = blockIdx.x * 4 + wv;
    int f = lane >> 3, hh = (lane >> 2) & 1, j = (lane & 3) << 1;
    float lsum = 0.f;
    for (int k = 0; k < 8; ++k) {
        int row = wid * 8 + k;
        int lab = labels[row];
        bf16x2 xv = *(const bf16x2*)(xsw + ((size_t)(row >> 5) * 4096) + f * 512 + hh * 256 + (row & 31) * 8 + j);
        float2 cs = *(const float2*)(csum + lab * DIM + 2 * lane);
        float x0 = (float)xv.x, x1 = (float)xv.y;
        float sd = fmaf(x0, x0, x1 * x1);        // selfdot partial
        float cd = fmaf(x0, cs.x, x1 * cs.y);    // classsum dot partial
#pragma unroll
        for (int m = 1; m < 64; m <<= 1) {
            sd += __shfl_xor(sd, m, 64);
            cd += __shfl_xor(cd, m, 64);
        }
        if (lane == 0) {
            float diag = exp2f(fmaf(sd, L2E10, -L2E10));
            float se   = fmaxf(se_acc[row] - diag, 1e-30f);
            float lse  = fmaf(log2f(se), LN2, 10.f);
            float cnt  = (float)(hist[lab] - 1);
            float ps   = 10.f * (cd - sd);       // exactly 0 when cnt==0
            lsum += (cnt * lse - ps) / (cnt + SMALL_VAL);
        }
    }
    if (lane == 0) part[wv] = lsum;
    __syncthreads();
    if (threadIdx.x == 0) atomicAdd(out, part[0] + part[1] + part[2] + part[3]);
}

extern "C" void kernel_launch(void* const* d_in, const int* in_sizes, int n_in,
                              void* d_out, int out_size, void* d_ws, size_t ws_size,
                              hipStream_t stream) {
    const float* emb  = (const float*)d_in[0];
    const int* labels = (const int*)d_in[1];

    char* ws = (char*)d_ws;
    bf16_t* xsw = (bf16_t*)ws;                                   // 2 MB swizzled bf16 X
    float* csum = (float*)(ws + (size_t)NN * DIM * 2);           // 512 KB class sums
    int*   hist = (int*)((char*)csum + (size_t)NCLASS * DIM * 4);// 4 KB
    float* se   = (float*)((char*)hist + NCLASS * 4);            // 32 KB

    // zero csum + hist + se in one contiguous memset
    hipMemsetAsync(csum, 0, (size_t)NCLASS * DIM * 4 + NCLASS * 4 + (size_t)NN * 4, stream);

    normalize_kernel<<<NN / 4, 256, 0, stream>>>(emb, labels, xsw, csum, hist, (float*)d_out);
    supcon_main<<<(NN / 128) * CSPLIT, 256, 0, stream>>>(xsw, se);
    finalize_kernel<<<NN / 32, 256, 0, stream>>>(xsw, se, csum, hist, labels, (float*)d_out);
}